// Round 5
// baseline (1349.489 us; speedup 1.0000x reference)
//
#include <hip/hip_runtime.h>

// HypergraphNN: out = Dv^-1/2 · H · De^-1 · H^T · Dv^-1/2 · X
// N=20000 nodes, E=8000 hyperedges, F=64 features, fp32 I/O.
//
// Three-tier workspace dispatch (ws_size is harness-controlled, unknown):
//   Path C (>=695 MB): fp16-convert H once + HhT; both matmuls as MFMA streams.
//   Path A (>=23 MB):  fp32 VALU pipeline with K-split partials.
//   Path S (>=2.2 MB): fp32 streaming pipeline, dv + X3 only, no partials.
//   else: no-op (never OOB-write the workspace).

constexpr int N = 20000;
constexpr int E = 8000;
constexpr int F = 64;
constexpr float EPS = 1e-10f;

typedef _Float16 half8 __attribute__((ext_vector_type(8)));
typedef float f32x4 __attribute__((ext_vector_type(4)));

// ===================== PATH C =====================

// K1a: Hh = fp16(H) row-major; dv[i] = 1/sqrt(rowsum + EPS)
__global__ __launch_bounds__(256) void c_k1a(const float* __restrict__ H,
                                             unsigned short* __restrict__ Hh,
                                             float* __restrict__ dv) {
  const int row = blockIdx.x;
  const float4* H4 = (const float4*)(H + (size_t)row * E);
  ushort4* Hh4 = (ushort4*)(Hh + (size_t)row * E);
  float s = 0.f;
  for (int c = threadIdx.x; c < E / 4; c += 256) {
    float4 v = H4[c];
    s += (v.x + v.y) + (v.z + v.w);
    ushort4 u;
    u.x = __builtin_bit_cast(unsigned short, (_Float16)v.x);
    u.y = __builtin_bit_cast(unsigned short, (_Float16)v.y);
    u.z = __builtin_bit_cast(unsigned short, (_Float16)v.z);
    u.w = __builtin_bit_cast(unsigned short, (_Float16)v.w);
    Hh4[c] = u;
  }
#pragma unroll
  for (int off = 32; off > 0; off >>= 1) s += __shfl_down(s, off, 64);
  __shared__ float red[4];
  if ((threadIdx.x & 63) == 0) red[threadIdx.x >> 6] = s;
  __syncthreads();
  if (threadIdx.x == 0) {
    float tot = (red[0] + red[1]) + (red[2] + red[3]);
    dv[row] = 1.0f / sqrtf(tot + EPS);
  }
}

// K1d: X1T[f][i] = fp16(32 * dv[i] * feat[i][f])   (transposed, scaled x32)
__global__ __launch_bounds__(256) void c_k1d(const float* __restrict__ feat,
                                             const float* __restrict__ dv,
                                             unsigned short* __restrict__ X1T) {
  const int i0 = blockIdx.x * 80;  // 250 blocks
  __shared__ float L[80 * 68];     // [80 i][64 f], pad to 68
  __shared__ float dvs[80];
  const int t = threadIdx.x;
  if (t < 80) dvs[t] = dv[i0 + t] * 32.0f;
  __syncthreads();
#pragma unroll
  for (int k = 0; k < 5; ++k) {  // 1280 float4 tasks
    int w = k * 256 + t;
    int row = w >> 4, c4 = w & 15;
    float4 v = *(const float4*)(feat + (size_t)(i0 + row) * F + c4 * 4);
    float d = dvs[row];
    v.x *= d; v.y *= d; v.z *= d; v.w *= d;
    *(float4*)(&L[row * 68 + c4 * 4]) = v;
  }
  __syncthreads();
#pragma unroll
  for (int k = 0; k < 3; ++k) {  // 640 uint4-write tasks
    int w = k * 256 + t;
    if (w < 640) {
      int f = w / 10, ch = w % 10;
      unsigned int d[4];
#pragma unroll
      for (int p = 0; p < 4; ++p) {
        unsigned int lo = __builtin_bit_cast(unsigned short, (_Float16)L[(ch * 8 + 2 * p) * 68 + f]);
        unsigned int hi = __builtin_bit_cast(unsigned short, (_Float16)L[(ch * 8 + 2 * p + 1) * 68 + f]);
        d[p] = lo | (hi << 16);
      }
      *(uint4*)(X1T + (size_t)f * N + i0 + ch * 8) = make_uint4(d[0], d[1], d[2], d[3]);
    }
  }
}

// K1b: HhT[e][i] = Hh[i][e]  (fp16 transpose via LDS tiles [160 i][64 e])
__global__ __launch_bounds__(256) void c_k1b(const unsigned short* __restrict__ Hh,
                                             unsigned short* __restrict__ HhT) {
  const int it = blockIdx.x / 125, et = blockIdx.x % 125;  // 125x125 tiles
  const int i0 = it * 160, e0 = et * 64;
  __shared__ unsigned short L1[160 * 72];  // row stride 72 (144B, 16B-aligned)
  __shared__ uint4 L2[64 * 20];            // [64 e][20 chunks of 8 i]
  const int t = threadIdx.x;
#pragma unroll
  for (int k = 0; k < 5; ++k) {  // load 1280 uint4 (8 fp16 each)
    int w = k * 256 + t;
    int row = w >> 3, c8 = w & 7;
    uint4 v = *(const uint4*)(Hh + (size_t)(i0 + row) * E + e0 + c8 * 8);
    *(uint4*)(&L1[row * 72 + c8 * 8]) = v;
  }
  __syncthreads();
#pragma unroll
  for (int k = 0; k < 5; ++k) {  // gather columns: lanes span e (2-way banks)
    int w = k * 256 + t;
    int e = w & 63, ic = w >> 6;  // ic 0..19
    unsigned int d[4];
#pragma unroll
    for (int p = 0; p < 4; ++p) {
      unsigned int lo = L1[(ic * 8 + 2 * p) * 72 + e];
      unsigned int hi = L1[(ic * 8 + 2 * p + 1) * 72 + e];
      d[p] = lo | (hi << 16);
    }
    L2[e * 20 + ic] = make_uint4(d[0], d[1], d[2], d[3]);
  }
  __syncthreads();
#pragma unroll
  for (int k = 0; k < 5; ++k) {  // coalesced 16B writes, 320B per e-row
    int w = k * 256 + t;
    int e = w / 20, ch = w % 20;
    uint4 v = L2[e * 20 + ch];
    *(uint4*)(HhT + (size_t)(e0 + e) * N + i0 + ch * 8) = v;
  }
}

// K2: X2p[c][e][f] = sum_{i in chunk c} HhT[e][i] * X1T[f][i]  (MFMA)
//     also de_sum[e] += sum_i Hh[i][e]  (A-fragment side-sum)
__global__ __launch_bounds__(128) void c_k2(const unsigned short* __restrict__ HhT,
                                            const unsigned short* __restrict__ X1T,
                                            float* __restrict__ X2p,
                                            float* __restrict__ de_sum) {
  const int wid = threadIdx.x >> 6, lane = threadIdx.x & 63;
  const int eb = blockIdx.x / 25, c = blockIdx.x % 25;
  const int e0 = eb * 160 + wid * 80;
  const int l15 = lane & 15, g = lane >> 4;
  f32x4 acc[5][4];
#pragma unroll
  for (int s = 0; s < 5; ++s)
#pragma unroll
    for (int t = 0; t < 4; ++t) acc[s][t] = (f32x4){0.f, 0.f, 0.f, 0.f};
  float dacc[5] = {0.f, 0.f, 0.f, 0.f, 0.f};
  const size_t kbase = (size_t)c * 800 + g * 8;
#pragma unroll 2
  for (int st = 0; st < 25; ++st) {
    const size_t k0 = kbase + st * 32;
    half8 a[5], b[4];
#pragma unroll
    for (int s = 0; s < 5; ++s)
      a[s] = *(const half8*)(HhT + (size_t)(e0 + s * 16 + l15) * N + k0);
#pragma unroll
    for (int t = 0; t < 4; ++t)
      b[t] = *(const half8*)(X1T + (size_t)(t * 16 + l15) * N + k0);
#pragma unroll
    for (int s = 0; s < 5; ++s)
#pragma unroll
      for (int t = 0; t < 4; ++t)
        acc[s][t] = __builtin_amdgcn_mfma_f32_16x16x32_f16(a[s], b[t], acc[s][t], 0, 0, 0);
#pragma unroll
    for (int s = 0; s < 5; ++s) {
      float sa = 0.f;
#pragma unroll
      for (int j = 0; j < 8; ++j) sa += (float)a[s][j];
      dacc[s] += sa;
    }
  }
#pragma unroll
  for (int s = 0; s < 5; ++s) {
    float v = dacc[s];
    v += __shfl_xor(v, 16);
    v += __shfl_xor(v, 32);
    if (lane < 16) atomicAdd(&de_sum[e0 + s * 16 + lane], v);
  }
#pragma unroll
  for (int s = 0; s < 5; ++s)
#pragma unroll
    for (int t = 0; t < 4; ++t)
#pragma unroll
      for (int r = 0; r < 4; ++r) {
        int e = e0 + s * 16 + g * 4 + r;  // C/D: col=lane&15, row=(lane>>4)*4+r
        int f = t * 16 + l15;
        X2p[((size_t)c * E + e) * F + f] = acc[s][t][r];
      }
}

// K2b: X3T[f][e] = fp16( 32 * (sum_c X2p[c][e][f]) / (de_sum[e] + EPS) )
__global__ __launch_bounds__(256) void c_k2b(const float* __restrict__ X2p,
                                             const float* __restrict__ de_sum,
                                             unsigned short* __restrict__ X3T) {
  const int gidx = blockIdx.x * 256 + threadIdx.x;  // E*F threads
  const int e = gidx >> 6, f = gidx & 63;
  float s = 0.f;
#pragma unroll
  for (int c = 0; c < 25; ++c) s += X2p[((size_t)c * E + e) * F + f];
  float v = s * (32.0f / (de_sum[e] + EPS));
  X3T[(size_t)f * E + e] = __builtin_bit_cast(unsigned short, (_Float16)v);
}

// K3: outp[c][i][f] = sum_{e in chunk c} Hh[i][e] * X3T[f][e]  (MFMA)
__global__ __launch_bounds__(128) void c_k3(const unsigned short* __restrict__ Hh,
                                            const unsigned short* __restrict__ X3T,
                                            float* __restrict__ outp) {
  const int wid = threadIdx.x >> 6, lane = threadIdx.x & 63;
  const int ib = blockIdx.x / 5, c = blockIdx.x % 5;
  const int i0 = ib * 32 + wid * 16;
  const int l15 = lane & 15, g = lane >> 4;
  f32x4 acc[4];
#pragma unroll
  for (int t = 0; t < 4; ++t) acc[t] = (f32x4){0.f, 0.f, 0.f, 0.f};
  const size_t kbase = (size_t)c * 1600 + g * 8;
#pragma unroll 2
  for (int st = 0; st < 50; ++st) {
    const size_t k0 = kbase + st * 32;
    half8 a = *(const half8*)(Hh + (size_t)(i0 + l15) * E + k0);
    half8 b[4];
#pragma unroll
    for (int t = 0; t < 4; ++t)
      b[t] = *(const half8*)(X3T + (size_t)(t * 16 + l15) * E + k0);
#pragma unroll
    for (int t = 0; t < 4; ++t)
      acc[t] = __builtin_amdgcn_mfma_f32_16x16x32_f16(a, b[t], acc[t], 0, 0, 0);
  }
#pragma unroll
  for (int t = 0; t < 4; ++t)
#pragma unroll
    for (int r = 0; r < 4; ++r) {
      int i = i0 + g * 4 + r;
      int f = t * 16 + l15;
      outp[((size_t)c * N + i) * F + f] = acc[t][r];
    }
}

// K3b: out[i][f] = dv[i] * (sum_c outp[c][i][f]) / 1024
__global__ __launch_bounds__(256) void c_k3b(const float* __restrict__ outp,
                                             const float* __restrict__ dv,
                                             float* __restrict__ out) {
  const int gidx = blockIdx.x * 256 + threadIdx.x;  // N*F threads
  const int i = gidx >> 6;
  float s = 0.f;
#pragma unroll
  for (int c = 0; c < 5; ++c) s += outp[(size_t)c * N * F + gidx];
  out[gidx] = s * dv[i] * (1.0f / 1024.0f);
}

// ===================== shared fp32 kernels (paths A & S) =====================

constexpr int NSPLIT = 10;
constexpr int RPS = N / NSPLIT;
constexpr int TI = 8;
constexpr int ET = 32;
constexpr int IT = 32;
constexpr int TEC = 64;

__global__ __launch_bounds__(256) void k_dv(const float* __restrict__ H,
                                            float* __restrict__ dvis) {
  const int row = blockIdx.x;
  const float4* H4 = reinterpret_cast<const float4*>(H + (size_t)row * E);
  float s = 0.f;
  for (int c = threadIdx.x; c < E / 4; c += 256) {
    float4 v = H4[c];
    s += (v.x + v.y) + (v.z + v.w);
  }
#pragma unroll
  for (int off = 32; off > 0; off >>= 1) s += __shfl_down(s, off, 64);
  __shared__ float red[4];
  if ((threadIdx.x & 63) == 0) red[threadIdx.x >> 6] = s;
  __syncthreads();
  if (threadIdx.x == 0) {
    float tot = (red[0] + red[1]) + (red[2] + red[3]);
    dvis[row] = 1.0f / sqrtf(tot + EPS);
  }
}

__global__ __launch_bounds__(256) void k_mm1(const float* __restrict__ H,
                                             const float* __restrict__ feat,
                                             const float* __restrict__ dvis,
                                             float* __restrict__ X2p,
                                             float* __restrict__ colsum_p) {
  const int split = blockIdx.x % NSPLIT;
  const int etile = blockIdx.x / NSPLIT;
  const int e0 = etile * ET;
  const int ibeg = split * RPS;
  const int t = threadIdx.x;
  const int el = t & 31;
  const int fg = t >> 5;
  const int srow = t >> 5;
  const int scol = t & 31;
  __shared__ float Hs[TI][ET];
  __shared__ float Xs[TI][F];
  float4 a0 = {0.f, 0.f, 0.f, 0.f};
  float4 a1 = {0.f, 0.f, 0.f, 0.f};
  float colsum = 0.f;
  for (int it2 = 0; it2 < RPS / TI; ++it2) {
    const int i0 = ibeg + it2 * TI;
    Hs[srow][scol] = H[(size_t)(i0 + srow) * E + e0 + scol];
    {
      const float dvv = dvis[i0 + srow];
      const float2 f2 = *reinterpret_cast<const float2*>(&feat[(size_t)(i0 + srow) * F + scol * 2]);
      float2 x;
      x.x = f2.x * dvv;
      x.y = f2.y * dvv;
      *reinterpret_cast<float2*>(&Xs[srow][scol * 2]) = x;
    }
    __syncthreads();
#pragma unroll
    for (int ii = 0; ii < TI; ++ii) {
      const float h = Hs[ii][el];
      colsum += h;
      const float4 xa = *reinterpret_cast<const float4*>(&Xs[ii][fg * 8]);
      const float4 xb = *reinterpret_cast<const float4*>(&Xs[ii][fg * 8 + 4]);
      a0.x += h * xa.x; a0.y += h * xa.y; a0.z += h * xa.z; a0.w += h * xa.w;
      a1.x += h * xb.x; a1.y += h * xb.y; a1.z += h * xb.z; a1.w += h * xb.w;
    }
    __syncthreads();
  }
  if (fg == 0) colsum_p[(size_t)split * E + e0 + el] = colsum;
  float* dst = X2p + ((size_t)split * E + e0 + el) * F + fg * 8;
  *reinterpret_cast<float4*>(dst) = a0;
  *reinterpret_cast<float4*>(dst + 4) = a1;
}

__global__ __launch_bounds__(256) void k_scale(const float* __restrict__ X2p,
                                               const float* __restrict__ colsum_p,
                                               float* __restrict__ X3) {
  const int gid = blockIdx.x * 256 + threadIdx.x;
  const int e = gid >> 6;
  float de = 0.f;
#pragma unroll
  for (int s = 0; s < NSPLIT; ++s) de += colsum_p[s * E + e];
  float v = 0.f;
#pragma unroll
  for (int s = 0; s < NSPLIT; ++s) v += X2p[(size_t)s * E * F + gid];
  X3[gid] = v / (de + EPS);
}

__global__ __launch_bounds__(256) void k_mm2(const float* __restrict__ H,
                                             const float* __restrict__ X3,
                                             const float* __restrict__ dvis,
                                             float* __restrict__ out) {
  const int i0 = blockIdx.x * IT;
  const int t = threadIdx.x;
  const int il = t & 31;
  const int fg = t >> 5;
  __shared__ float Hs[IT][TEC + 1];
  __shared__ float Xs[TEC][F];
  float4 a0 = {0.f, 0.f, 0.f, 0.f};
  float4 a1 = {0.f, 0.f, 0.f, 0.f};
  for (int et = 0; et < E / TEC; ++et) {
    const int e0 = et * TEC;
#pragma unroll
    for (int k = 0; k < 8; ++k) {
      const int idx = t + k * 256;
      Hs[idx >> 6][idx & 63] = H[(size_t)(i0 + (idx >> 6)) * E + e0 + (idx & 63)];
    }
#pragma unroll
    for (int k = 0; k < 4; ++k) {
      const int idx4 = t + k * 256;
      *reinterpret_cast<float4*>(&Xs[idx4 >> 4][(idx4 & 15) * 4]) =
          *reinterpret_cast<const float4*>(&X3[(size_t)(e0 + (idx4 >> 4)) * F + (idx4 & 15) * 4]);
    }
    __syncthreads();
#pragma unroll 8
    for (int ee = 0; ee < TEC; ++ee) {
      const float h = Hs[il][ee];
      const float4 xa = *reinterpret_cast<const float4*>(&Xs[ee][fg * 8]);
      const float4 xb = *reinterpret_cast<const float4*>(&Xs[ee][fg * 8 + 4]);
      a0.x += h * xa.x; a0.y += h * xa.y; a0.z += h * xa.z; a0.w += h * xa.w;
      a1.x += h * xb.x; a1.y += h * xb.y; a1.z += h * xb.z; a1.w += h * xb.w;
    }
    __syncthreads();
  }
  const float dvv = dvis[i0 + il];
  float4 r0, r1;
  r0.x = a0.x * dvv; r0.y = a0.y * dvv; r0.z = a0.z * dvv; r0.w = a0.w * dvv;
  r1.x = a1.x * dvv; r1.y = a1.y * dvv; r1.z = a1.z * dvv; r1.w = a1.w * dvv;
  float* dst = out + (size_t)(i0 + il) * F + fg * 8;
  *reinterpret_cast<float4*>(dst) = r0;
  *reinterpret_cast<float4*>(dst + 4) = r1;
}

// ---- Path S mm1: un-split (grid = E/ET), fuses d_e colsum + De^-1 scale ----
__global__ __launch_bounds__(256) void s_mm1(const float* __restrict__ H,
                                             const float* __restrict__ feat,
                                             const float* __restrict__ dvis,
                                             float* __restrict__ X3) {
  const int e0 = blockIdx.x * ET;
  const int t = threadIdx.x;
  const int el = t & 31;
  const int fg = t >> 5;
  const int srow = t >> 5;
  const int scol = t & 31;
  __shared__ float Hs[TI][ET];
  __shared__ float Xs[TI][F];
  __shared__ float des[ET];
  float4 a0 = {0.f, 0.f, 0.f, 0.f};
  float4 a1 = {0.f, 0.f, 0.f, 0.f};
  float colsum = 0.f;
  for (int it2 = 0; it2 < N / TI; ++it2) {
    const int i0 = it2 * TI;
    Hs[srow][scol] = H[(size_t)(i0 + srow) * E + e0 + scol];
    {
      const float dvv = dvis[i0 + srow];
      const float2 f2 = *reinterpret_cast<const float2*>(&feat[(size_t)(i0 + srow) * F + scol * 2]);
      float2 x;
      x.x = f2.x * dvv;
      x.y = f2.y * dvv;
      *reinterpret_cast<float2*>(&Xs[srow][scol * 2]) = x;
    }
    __syncthreads();
#pragma unroll
    for (int ii = 0; ii < TI; ++ii) {
      const float h = Hs[ii][el];
      colsum += h;
      const float4 xa = *reinterpret_cast<const float4*>(&Xs[ii][fg * 8]);
      const float4 xb = *reinterpret_cast<const float4*>(&Xs[ii][fg * 8 + 4]);
      a0.x += h * xa.x; a0.y += h * xa.y; a0.z += h * xa.z; a0.w += h * xa.w;
      a1.x += h * xb.x; a1.y += h * xb.y; a1.z += h * xb.z; a1.w += h * xb.w;
    }
    __syncthreads();
  }
  if (fg == 0) des[el] = colsum;
  __syncthreads();
  const float inv = 1.0f / (des[el] + EPS);
  float4 r0, r1;
  r0.x = a0.x * inv; r0.y = a0.y * inv; r0.z = a0.z * inv; r0.w = a0.w * inv;
  r1.x = a1.x * inv; r1.y = a1.y * inv; r1.z = a1.z * inv; r1.w = a1.w * inv;
  float* dst = X3 + (size_t)(e0 + el) * F + fg * 8;
  *reinterpret_cast<float4*>(dst) = r0;
  *reinterpret_cast<float4*>(dst + 4) = r1;
}

// ===================== launch =====================

extern "C" void kernel_launch(void* const* d_in, const int* in_sizes, int n_in,
                              void* d_out, int out_size, void* d_ws, size_t ws_size,
                              hipStream_t stream) {
  const float* H = (const float*)d_in[0];     // [N, E]
  const float* feat = (const float*)d_in[1];  // [N, F]
  float* out = (float*)d_out;                 // [N, F]

  const size_t needC = 695000000;                                  // fp16 MFMA path
  const size_t needA = (size_t)(N + NSPLIT * E + NSPLIT * E * F + E * F) * 4;  // ~22.9 MB
  const size_t needS = (size_t)(N + E * F) * 4;                    // ~2.13 MB

  if (ws_size >= needC) {
    char* w = (char*)d_ws;
    unsigned short* Hh = (unsigned short*)w;
    unsigned short* HhT = (unsigned short*)(w + 320000000);
    float* X2p = (float*)(w + 640000000);      // 51.2e6 B
    float* outp = X2p;                          // 25.6e6 B, reused after K2b
    unsigned short* X1T = (unsigned short*)(w + 691200000);  // 2.56e6 B
    unsigned short* X3T = (unsigned short*)(w + 693760000);  // 1.024e6 B
    float* dv = (float*)(w + 694784000);        // 80e3 B
    float* de_sum = (float*)(w + 694864000);    // 32e3 B

    hipMemsetAsync(de_sum, 0, E * sizeof(float), stream);
    c_k1a<<<N, 256, 0, stream>>>(H, Hh, dv);
    c_k1d<<<250, 256, 0, stream>>>(feat, dv, X1T);
    c_k1b<<<15625, 256, 0, stream>>>(Hh, HhT);
    c_k2<<<1250, 128, 0, stream>>>(HhT, X1T, X2p, de_sum);
    c_k2b<<<2000, 256, 0, stream>>>(X2p, de_sum, X3T);
    c_k3<<<3125, 128, 0, stream>>>(Hh, X3T, outp);
    c_k3b<<<5000, 256, 0, stream>>>(outp, dv, out);
  } else if (ws_size >= needA) {
    float* ws = (float*)d_ws;
    float* dvis = ws;
    float* colsum_p = dvis + N;
    float* X2p = colsum_p + NSPLIT * E;
    float* X3 = X2p + (size_t)NSPLIT * E * F;
    k_dv<<<N, 256, 0, stream>>>(H, dvis);
    k_mm1<<<(E / ET) * NSPLIT, 256, 0, stream>>>(H, feat, dvis, X2p, colsum_p);
    k_scale<<<E * F / 256, 256, 0, stream>>>(X2p, colsum_p, X3);
    k_mm2<<<N / IT, 256, 0, stream>>>(H, X3, dvis, out);
  } else if (ws_size >= needS) {
    float* ws = (float*)d_ws;
    float* dvis = ws;       // N floats
    float* X3 = dvis + N;   // E*F floats
    k_dv<<<N, 256, 0, stream>>>(H, dvis);
    s_mm1<<<E / ET, 256, 0, stream>>>(H, feat, dvis, X3);
    k_mm2<<<N / IT, 256, 0, stream>>>(H, X3, dvis, out);
  }
  // else: workspace too small for any path — do nothing rather than OOB-write.
}